// Round 10
// baseline (3371.621 us; speedup 1.0000x reference)
//
#include <hip/hip_runtime.h>
#include <math.h>

#define HID 64
#define TST 2048
#define CH 16              // timesteps per chunk
#define NCH (TST / CH)     // 128 chunks
#define EPSN 1e-5f

typedef float v2f __attribute__((ext_vector_type(2)));

#define REP32(M) M(0) M(1) M(2) M(3) M(4) M(5) M(6) M(7) \
                 M(8) M(9) M(10) M(11) M(12) M(13) M(14) M(15) \
                 M(16) M(17) M(18) M(19) M(20) M(21) M(22) M(23) \
                 M(24) M(25) M(26) M(27) M(28) M(29) M(30) M(31)

// ---------------------------------------------------------------------------
// Kernel 1: x = GELU(LayerNorm(ce @ w1 + b1))  -> staged into d_out (unchanged)
// ---------------------------------------------------------------------------
__global__ void k_inproj(const float* __restrict__ ce, const float* __restrict__ w1,
                         const float* __restrict__ b1, const float* __restrict__ g1,
                         const float* __restrict__ be1, float* __restrict__ xout,
                         int nrows) {
    const int lane = threadIdx.x & 63;
    const int wave = threadIdx.x >> 6;
    const long row = (long)blockIdx.x * 4 + wave;
    if (row >= nrows) return;
    const float* cr = ce + row * 6;
    float acc = b1[lane];
    acc += cr[0] * w1[0 * HID + lane];
    acc += cr[1] * w1[1 * HID + lane];
    acc += cr[2] * w1[2 * HID + lane];
    acc += cr[3] * w1[3 * HID + lane];
    acc += cr[4] * w1[4 * HID + lane];
    acc += cr[5] * w1[5 * HID + lane];
    float s = acc;
#pragma unroll
    for (int m = 32; m >= 1; m >>= 1) s += __shfl_xor(s, m, 64);
    const float mean = s * (1.0f / 64.0f);
    const float d = acc - mean;
    float q = d * d;
#pragma unroll
    for (int m = 32; m >= 1; m >>= 1) q += __shfl_xor(q, m, 64);
    const float var = q * (1.0f / 64.0f);
    const float xn = d * rsqrtf(var + EPSN) * g1[lane] + be1[lane];
    const float ge = 0.5f * xn * (1.0f + erff(xn * 0.70710678118654752440f));
    xout[row * HID + lane] = ge;
}

// ---------------------------------------------------------------------------
// Kernel 2: GRU scan — R8 structure, TWO SEQUENCES PER BLOCK, interleaved.
//
// Aggregated evidence R0-R9: every structure (4/8-wave, barriered/chunked,
// spilled/rematted/AGPR-resident, LDS-broadcast/readlane) lands at
// 1840-2000 cy/step with VALUBusy <= 29% — SIMDs are mostly IDLE. LDS-op
// count varied 5x and VALU count 3x across rounds with no time change:
// neither pipe's throughput is the limit. The invariant is the serial
// per-step latency chain (gi read -> combine -> h-broadcast roundtrip ->
// matvec) ~= 1850 cy at 1-wave/SIMD occupancy. Discriminating experiment:
// interleave two independent sequences in the same waves (grid B/2=128).
// Latency-bound -> chains overlap -> ~2x; issue-bound -> ~0.5x. Weights
// are shared (zero extra registers); all per-seq buffers duplicated
// (LDS 80.5 KB < 160 KB). Per-sequence arithmetic identical to R8.
//   wave 0: W_hh (A/B/C, AGPR-pinned), scan: step(seqA); step(seqB).
//   waves 1-2: W_ih gates, gi for chunk p, both seqs.
//   wave 3: w2 column, LN epilogue chunk p-2 + x prefetch, both seqs.
// ---------------------------------------------------------------------------
__global__ __launch_bounds__(256, 1)
__attribute__((amdgpu_waves_per_eu(1, 1)))
void k_gru(float* xo,
           const float* __restrict__ W_ih, const float* __restrict__ b_ih,
           const float* __restrict__ W_hh, const float* __restrict__ b_hh,
           const float* __restrict__ w2, const float* __restrict__ b2,
           const float* __restrict__ g2, const float* __restrict__ be2) {
    __shared__ __align__(16) float4 xbuf[2][2][CH][16];    // 16 KB [seq][dbuf]
    __shared__ __align__(16) float gibuf[2][2][CH][192];   // 48 KB
    __shared__ __align__(16) float hist[2][2][CH][HID];    // 16 KB
    __shared__ __align__(16) float hbuf[2][HID];           // 512 B h broadcast

    const int tid = threadIdx.x;
    const int lane = tid & 63;
    const int wv = tid >> 6;
    float* xb0 = xo + (size_t)(2 * blockIdx.x) * TST * HID;
    float* xb1 = xo + (size_t)(2 * blockIdx.x + 1) * TST * HID;

#define DECLW(i) v2f A##i = {0.f, 0.f}, B##i = {0.f, 0.f}, C##i = {0.f, 0.f};
    REP32(DECLW)
    float sc0 = 0.f, sc1 = 0.f, sc2 = 0.f;   // per-wave scalar params

    if (wv == 0) {
        const v2f* r0 = (const v2f*)(W_hh + (size_t)lane * HID);
        const v2f* r1 = (const v2f*)(W_hh + (size_t)(64 + lane) * HID);
        const v2f* r2 = (const v2f*)(W_hh + (size_t)(128 + lane) * HID);
#define LW0(i) A##i = r0[i]; B##i = r1[i]; C##i = r2[i];
        REP32(LW0)
        sc0 = b_hh[lane]; sc1 = b_hh[64 + lane]; sc2 = b_hh[128 + lane];
        hbuf[0][lane] = 0.0f; hbuf[1][lane] = 0.0f;
    } else if (wv == 1) {
        const v2f* rA = (const v2f*)(W_ih + (size_t)lane * HID);
        const v2f* rB = (const v2f*)(W_ih + (size_t)(128 + lane) * HID);
#define LW1(i) A##i = rA[i]; B##i = rB[i];
        REP32(LW1)
        sc0 = b_ih[lane]; sc1 = b_ih[128 + lane];
    } else if (wv == 2) {
        const v2f* rC = (const v2f*)(W_ih + (size_t)(64 + lane) * HID);
#define LW2(i) A##i = rC[i];
        REP32(LW2)
        sc0 = b_ih[64 + lane];
    } else {
#define LW3(i) A##i.x = w2[(size_t)(2 * (i)) * HID + lane]; \
               A##i.y = w2[(size_t)(2 * (i) + 1) * HID + lane];
        REP32(LW3)
        sc0 = b2[lane]; sc1 = g2[lane]; sc2 = be2[lane];
    }

    // Park weights in the AGPR file (R8 allocation, best measured).
#define PINW(i) asm volatile("" : "+a"(A##i), "+a"(B##i), "+a"(C##i));
    REP32(PINW)

    // Prefill chunk 0 of both sequences (256 float4 each).
    ((float4*)&xbuf[0][0][0][0])[tid] = ((const float4*)xb0)[tid];
    ((float4*)&xbuf[1][0][0][0])[tid] = ((const float4*)xb1)[tid];
    float hA = 0.0f, hB = 0.0f;
    __syncthreads();

#define SFMA(i) { const v2f h2 = hv[i]; \
                  if ((i) & 1) { ar1 += A##i * h2; az1 += B##i * h2; an1 += C##i * h2; } \
                  else         { ar0 += A##i * h2; az0 += B##i * h2; an0 += C##i * h2; } }

#define SCANSTEP(gp, hp, q, hreg) { \
    const float gr = gp[t * 192 + lane]; \
    const float gz = gp[t * 192 + 64 + lane]; \
    const float gn = gp[t * 192 + 128 + lane]; \
    const v2f* hv = (const v2f*)&hbuf[q][0]; \
    v2f ar0 = {0.f, 0.f}, ar1 = {0.f, 0.f}; \
    v2f az0 = {0.f, 0.f}, az1 = {0.f, 0.f}; \
    v2f an0 = {0.f, 0.f}, an1 = {0.f, 0.f}; \
    REP32(SFMA) \
    const v2f arv = ar0 + ar1; \
    const v2f azv = az0 + az1; \
    const v2f anv = an0 + an1; \
    const float rpre = gr + arv.x + arv.y + sc0; \
    const float zpre = gz + azv.x + azv.y + sc1; \
    const float hn = anv.x + anv.y + sc2; \
    const float r = 1.0f / (1.0f + __expf(-rpre)); \
    const float z = 1.0f / (1.0f + __expf(-zpre)); \
    const float pre = gn + r * hn; \
    const float e2 = __expf(2.0f * pre); \
    const float n = 1.0f - 2.0f / (e2 + 1.0f); \
    hreg = (1.0f - z) * n + z * hreg; \
    hbuf[q][lane] = hreg; \
    hp[t * HID + lane] = hreg; }

#define GFMA1(i) { const v2f x2 = xv[i]; \
                   if ((i) & 1) { aA1 += A##i * x2; aB1 += B##i * x2; } \
                   else         { aA0 += A##i * x2; aB0 += B##i * x2; } }
#define GFMA2(i) { const v2f x2 = xv[i]; \
                   if ((i) & 1) { aA1 += A##i * x2; } \
                   else         { aA0 += A##i * x2; } }

#define GISTEP(q) { \
    const v2f* xv = (const v2f*)&xbuf[q][p & 1][t][0]; \
    float* gp = (float*)&gibuf[q][p & 1][0][0]; \
    v2f aA0 = {0.f, 0.f}, aA1 = {0.f, 0.f}; \
    v2f aB0 = {0.f, 0.f}, aB1 = {0.f, 0.f}; \
    if (wv == 1) { \
        REP32(GFMA1) \
        gp[t * 192 + lane] = aA0.x + aA0.y + aA1.x + aA1.y + sc0; \
        gp[t * 192 + 128 + lane] = aB0.x + aB0.y + aB1.x + aB1.y + sc1; \
    } else { \
        REP32(GFMA2) \
        gp[t * 192 + 64 + lane] = aA0.x + aA0.y + aA1.x + aA1.y + sc0; \
    } }

#define EFMA(i) { const v2f h2 = hr[i]; \
                  if ((i) & 1) { a21 += A##i * h2; } else { a20 += A##i * h2; } }

#define EPI(q, xbq) { \
    const float* hp = (const float*)&hist[q][ce & 1][0][0]; \
    _Pragma("unroll 1") \
    for (int half = 0; half < 2; ++half) { \
        float yv[8], sv[8], qv[8]; \
        _Pragma("unroll") \
        for (int u = 0; u < 8; ++u) { \
            const int t = half * 8 + u; \
            const v2f* hr = (const v2f*)(hp + t * HID); \
            v2f a20 = {0.f, 0.f}, a21 = {0.f, 0.f}; \
            REP32(EFMA) \
            yv[u] = sc0 + a20.x + a20.y + a21.x + a21.y; \
        } \
        _Pragma("unroll") \
        for (int u = 0; u < 8; ++u) { sv[u] = yv[u]; qv[u] = yv[u] * yv[u]; } \
        _Pragma("unroll") \
        for (int m = 32; m >= 1; m >>= 1) { \
            _Pragma("unroll") \
            for (int u = 0; u < 8; ++u) sv[u] += __shfl_xor(sv[u], m, 64); \
            _Pragma("unroll") \
            for (int u = 0; u < 8; ++u) qv[u] += __shfl_xor(qv[u], m, 64); \
        } \
        _Pragma("unroll") \
        for (int u = 0; u < 8; ++u) { \
            const int t = half * 8 + u; \
            const float mean = sv[u] * (1.0f / 64.0f); \
            const float var = qv[u] * (1.0f / 64.0f) - mean * mean; \
            const float dd = yv[u] - mean; \
            xbq[(size_t)(ce * CH + t) * HID + lane] = \
                dd * rsqrtf(var + EPSN) * sc1 + sc2; \
        } \
    } }

#define PREF(q, xbq) { \
    const float4* src = (const float4*)(xbq + (size_t)(p + 1) * CH * HID); \
    float4* dst = (float4*)&xbuf[q][(p + 1) & 1][0][0]; \
    _Pragma("unroll") \
    for (int q2 = 0; q2 < 4; ++q2) dst[lane + q2 * 64] = src[lane + q2 * 64]; }

    for (int p = 0; p <= NCH + 1; ++p) {
        if (wv == 0) {
            if (p >= 1 && p <= NCH) {
                const int c = p - 1;
                const float* gpA = (const float*)&gibuf[0][c & 1][0][0];
                const float* gpB = (const float*)&gibuf[1][c & 1][0][0];
                float* hpA = (float*)&hist[0][c & 1][0][0];
                float* hpB = (float*)&hist[1][c & 1][0][0];
#pragma unroll 1
                for (int t = 0; t < CH; ++t) {
                    SCANSTEP(gpA, hpA, 0, hA)
                    SCANSTEP(gpB, hpB, 1, hB)
                }
            }
        } else if (wv == 1 || wv == 2) {
            if (p < NCH) {
#pragma unroll 1
                for (int t = 0; t < CH; ++t) {
                    GISTEP(0)
                    GISTEP(1)
                }
            }
        } else {
            if (p >= 2) {
                const int ce = p - 2;
                EPI(0, xb0)
                EPI(1, xb1)
            }
            if (p + 1 < NCH) {
                PREF(0, xb0)
                PREF(1, xb1)
            }
        }
        __syncthreads();
    }
}

extern "C" void kernel_launch(void* const* d_in, const int* in_sizes, int n_in,
                              void* d_out, int out_size, void* d_ws, size_t ws_size,
                              hipStream_t stream) {
    const float* ce  = (const float*)d_in[0];
    const float* w1  = (const float*)d_in[1];
    const float* b1  = (const float*)d_in[2];
    const float* g1  = (const float*)d_in[3];
    const float* be1 = (const float*)d_in[4];
    const float* Wih = (const float*)d_in[5];
    const float* bih = (const float*)d_in[6];
    const float* Whh = (const float*)d_in[7];
    const float* bhh = (const float*)d_in[8];
    const float* w2  = (const float*)d_in[9];
    const float* b2  = (const float*)d_in[10];
    const float* g2  = (const float*)d_in[11];
    const float* be2 = (const float*)d_in[12];
    float* out = (float*)d_out;

    const int nrows = in_sizes[0] / 6;   // B*T
    const int B = nrows / TST;           // 256 (even)

    k_inproj<<<(nrows + 3) / 4, 256, 0, stream>>>(ce, w1, b1, g1, be1, out, nrows);
    k_gru<<<B / 2, 256, 0, stream>>>(out, Wih, bih, Whh, bhh, w2, b2, g2, be2);
}

// Round 11
// 1928.690 us; speedup vs baseline: 1.7481x; 1.7481x over previous
//
#include <hip/hip_runtime.h>
#include <math.h>

#define HID 64
#define TST 2048
#define CH 16              // timesteps per chunk
#define NCH (TST / CH)     // 128 chunks
#define EPSN 1e-5f

typedef float v2f __attribute__((ext_vector_type(2)));

#define REP32(M) M(0) M(1) M(2) M(3) M(4) M(5) M(6) M(7) \
                 M(8) M(9) M(10) M(11) M(12) M(13) M(14) M(15) \
                 M(16) M(17) M(18) M(19) M(20) M(21) M(22) M(23) \
                 M(24) M(25) M(26) M(27) M(28) M(29) M(30) M(31)

// ---------------------------------------------------------------------------
// Kernel 1: x = GELU(LayerNorm(ce @ w1 + b1))  -> staged into d_out (unchanged)
// ---------------------------------------------------------------------------
__global__ void k_inproj(const float* __restrict__ ce, const float* __restrict__ w1,
                         const float* __restrict__ b1, const float* __restrict__ g1,
                         const float* __restrict__ be1, float* __restrict__ xout,
                         int nrows) {
    const int lane = threadIdx.x & 63;
    const int wave = threadIdx.x >> 6;
    const long row = (long)blockIdx.x * 4 + wave;
    if (row >= nrows) return;
    const float* cr = ce + row * 6;
    float acc = b1[lane];
    acc += cr[0] * w1[0 * HID + lane];
    acc += cr[1] * w1[1 * HID + lane];
    acc += cr[2] * w1[2 * HID + lane];
    acc += cr[3] * w1[3 * HID + lane];
    acc += cr[4] * w1[4 * HID + lane];
    acc += cr[5] * w1[5 * HID + lane];
    float s = acc;
#pragma unroll
    for (int m = 32; m >= 1; m >>= 1) s += __shfl_xor(s, m, 64);
    const float mean = s * (1.0f / 64.0f);
    const float d = acc - mean;
    float q = d * d;
#pragma unroll
    for (int m = 32; m >= 1; m >>= 1) q += __shfl_xor(q, m, 64);
    const float var = q * (1.0f / 64.0f);
    const float xn = d * rsqrtf(var + EPSN) * g1[lane] + be1[lane];
    const float ge = 0.5f * xn * (1.0f + erff(xn * 0.70710678118654752440f));
    xout[row * HID + lane] = ge;
}

// ---------------------------------------------------------------------------
// Kernel 2: GRU scan, 4 waves (R8 structure) with PER-ITERATION AGPR re-pins.
//
// Evidence synthesis R0-R10:
//  - R10 (2 seqs/block): dur scaled exactly 2x -> per-step cost is wave-0's
//    serial instruction+reload stream; compiler never overlaps independent
//    chains across the step's waitcnt structure. seqs==CUs, so packing can't
//    help: wall time = 2048 x per-step cost. Only lever: SHORTEN THE STEP.
//  - R5 proved "+a" pins CAN hold (VGPR 60->92) for 64-reg sets; R8's
//    one-time pin did NOT hold the 192-reg set (VGPR stayed 132 = no-pin
//    value): point-pins don't constrain lifetimes (R3 lesson). The step is
//    still paying per-iteration weight reloads from L2.
//  - R9 showed spills are visible as WRITE_SIZE growth (131->144 MB).
// Fix: re-pin the weight registers INSIDE every hot loop. The pin's "+a"
// makes the value an asm output (non-rematerializable) and re-asserts AGPR
// residency each iteration -> cheapest legal allocation is to keep weights
// parked in AGPRs for the whole loop. Falsifiers: VGPR>=200 & WRITE_SIZE
// ==131072 KB -> held; VGPR~132 or WRITE_SIZE up -> pivot structures.
// ---------------------------------------------------------------------------
__global__ __launch_bounds__(256, 1)
__attribute__((amdgpu_waves_per_eu(1, 1)))
void k_gru(float* xo,
           const float* __restrict__ W_ih, const float* __restrict__ b_ih,
           const float* __restrict__ W_hh, const float* __restrict__ b_hh,
           const float* __restrict__ w2, const float* __restrict__ b2,
           const float* __restrict__ g2, const float* __restrict__ be2) {
    __shared__ __align__(16) float4 xbuf[2][CH][16];    // 8 KB  x chunks
    __shared__ __align__(16) float gibuf[2][CH][192];   // 24 KB gi preacts
    __shared__ __align__(16) float hist[2][CH][HID];    // 8 KB  h history
    __shared__ __align__(16) float hbuf[HID];           // h broadcast (wave 0)

    const int tid = threadIdx.x;
    const int lane = tid & 63;
    const int wv = tid >> 6;
    float* xb = xo + (size_t)blockIdx.x * TST * HID;

#define DECLW(i) v2f A##i = {0.f, 0.f}, B##i = {0.f, 0.f}, C##i = {0.f, 0.f};
    REP32(DECLW)
    float sc0 = 0.f, sc1 = 0.f, sc2 = 0.f;   // per-wave scalar params

    if (wv == 0) {
        const v2f* r0 = (const v2f*)(W_hh + (size_t)lane * HID);
        const v2f* r1 = (const v2f*)(W_hh + (size_t)(64 + lane) * HID);
        const v2f* r2 = (const v2f*)(W_hh + (size_t)(128 + lane) * HID);
#define LW0(i) A##i = r0[i]; B##i = r1[i]; C##i = r2[i];
        REP32(LW0)
        sc0 = b_hh[lane]; sc1 = b_hh[64 + lane]; sc2 = b_hh[128 + lane];
        hbuf[lane] = 0.0f;
    } else if (wv == 1) {
        const v2f* rA = (const v2f*)(W_ih + (size_t)lane * HID);
        const v2f* rB = (const v2f*)(W_ih + (size_t)(128 + lane) * HID);
#define LW1(i) A##i = rA[i]; B##i = rB[i];
        REP32(LW1)
        sc0 = b_ih[lane]; sc1 = b_ih[128 + lane];
    } else if (wv == 2) {
        const v2f* rC = (const v2f*)(W_ih + (size_t)(64 + lane) * HID);
#define LW2(i) A##i = rC[i];
        REP32(LW2)
        sc0 = b_ih[64 + lane];
    } else {
#define LW3(i) A##i.x = w2[(size_t)(2 * (i)) * HID + lane]; \
               A##i.y = w2[(size_t)(2 * (i) + 1) * HID + lane];
        REP32(LW3)
        sc0 = b2[lane]; sc1 = g2[lane]; sc2 = be2[lane];
    }

    // Initial park in the AGPR file...
#define PINW(i) asm volatile("" : "+a"(A##i), "+a"(B##i), "+a"(C##i));
    REP32(PINW)
    // ...and re-pinned at the top of every hot-loop iteration (see loops).

    {
        const float4* src = (const float4*)xb;
        ((float4*)xbuf[0])[tid] = src[tid];
    }
    float h_reg = 0.0f;
    __syncthreads();

    for (int p = 0; p <= NCH + 1; ++p) {
        if (wv == 0) {
            if (p >= 1 && p <= NCH) {
                const int c = p - 1;
                const float* gp = (const float*)gibuf[c & 1];
                float* hp = (float*)hist[c & 1];
#pragma unroll 1
                for (int t = 0; t < CH; ++t) {
                    REP32(PINW)          // per-iteration residency re-assert
                    const float gr = gp[t * 192 + lane];
                    const float gz = gp[t * 192 + 64 + lane];
                    const float gn = gp[t * 192 + 128 + lane];
                    const v2f* hv = (const v2f*)hbuf;
                    // 2-way split accumulators: halve the dependent FMA chain
                    v2f ar0 = {0.f, 0.f}, ar1 = {0.f, 0.f};
                    v2f az0 = {0.f, 0.f}, az1 = {0.f, 0.f};
                    v2f an0 = {0.f, 0.f}, an1 = {0.f, 0.f};
#define SFMA(i) { const v2f h2 = hv[i]; \
                  if ((i) & 1) { ar1 += A##i * h2; az1 += B##i * h2; an1 += C##i * h2; } \
                  else         { ar0 += A##i * h2; az0 += B##i * h2; an0 += C##i * h2; } }
                    REP32(SFMA)
                    const v2f arv = ar0 + ar1;
                    const v2f azv = az0 + az1;
                    const v2f anv = an0 + an1;
                    const float rpre = gr + arv.x + arv.y + sc0;
                    const float zpre = gz + azv.x + azv.y + sc1;
                    const float hn = anv.x + anv.y + sc2;
                    const float r = 1.0f / (1.0f + __expf(-rpre));
                    const float z = 1.0f / (1.0f + __expf(-zpre));
                    const float pre = gn + r * hn;
                    const float e2 = __expf(2.0f * pre);
                    const float n = 1.0f - 2.0f / (e2 + 1.0f);
                    h_reg = (1.0f - z) * n + z * h_reg;
                    hbuf[lane] = h_reg;
                    hp[t * HID + lane] = h_reg;
                }
            }
        } else if (wv == 1 || wv == 2) {
            if (p < NCH) {
                const float4* xc = (const float4*)xbuf[p & 1];
                float* gp = (float*)gibuf[p & 1];
#pragma unroll 1
                for (int t = 0; t < CH; ++t) {
                    REP32(PINW)          // per-iteration residency re-assert
                    const v2f* xv = (const v2f*)(xc + t * 16);
                    v2f aA0 = {0.f, 0.f}, aA1 = {0.f, 0.f};
                    v2f aB0 = {0.f, 0.f}, aB1 = {0.f, 0.f};
                    if (wv == 1) {
#define GFMA1(i) { const v2f x2 = xv[i]; \
                   if ((i) & 1) { aA1 += A##i * x2; aB1 += B##i * x2; } \
                   else         { aA0 += A##i * x2; aB0 += B##i * x2; } }
                        REP32(GFMA1)
                        gp[t * 192 + lane] = aA0.x + aA0.y + aA1.x + aA1.y + sc0;
                        gp[t * 192 + 128 + lane] = aB0.x + aB0.y + aB1.x + aB1.y + sc1;
                    } else {
#define GFMA2(i) { const v2f x2 = xv[i]; \
                   if ((i) & 1) { aA1 += A##i * x2; } \
                   else         { aA0 += A##i * x2; } }
                        REP32(GFMA2)
                        gp[t * 192 + 64 + lane] = aA0.x + aA0.y + aA1.x + aA1.y + sc0;
                    }
                }
            }
        } else {
            // ---- epilogue for chunk p-2: LN over 16 timesteps, 2 halves of 8 ----
            if (p >= 2) {
                const int ce = p - 2;
                const float* hp = (const float*)hist[ce & 1];
#pragma unroll 1
                for (int half = 0; half < 2; ++half) {
                    REP32(PINW)          // per-iteration residency re-assert
                    float yv[8], sv[8], qv[8];
#pragma unroll
                    for (int u = 0; u < 8; ++u) {
                        const int t = half * 8 + u;
                        const v2f* hr = (const v2f*)(hp + t * HID);
                        v2f a20 = {0.f, 0.f}, a21 = {0.f, 0.f};
#define EFMA(i) { const v2f h2 = hr[i]; \
                  if ((i) & 1) { a21 += A##i * h2; } else { a20 += A##i * h2; } }
                        REP32(EFMA)
                        yv[u] = sc0 + a20.x + a20.y + a21.x + a21.y;
                    }
#pragma unroll
                    for (int u = 0; u < 8; ++u) { sv[u] = yv[u]; qv[u] = yv[u] * yv[u]; }
#pragma unroll
                    for (int m = 32; m >= 1; m >>= 1) {
#pragma unroll
                        for (int u = 0; u < 8; ++u) sv[u] += __shfl_xor(sv[u], m, 64);
#pragma unroll
                        for (int u = 0; u < 8; ++u) qv[u] += __shfl_xor(qv[u], m, 64);
                    }
#pragma unroll
                    for (int u = 0; u < 8; ++u) {
                        const int t = half * 8 + u;
                        const float mean = sv[u] * (1.0f / 64.0f);
                        const float var = qv[u] * (1.0f / 64.0f) - mean * mean;
                        const float dd = yv[u] - mean;
                        xb[(size_t)(ce * CH + t) * HID + lane] =
                            dd * rsqrtf(var + EPSN) * sc1 + sc2;
                    }
                }
            }
            // prefetch x chunk p+1
            if (p + 1 < NCH) {
                const float4* src = (const float4*)(xb + (size_t)(p + 1) * CH * HID);
                float4* dst = (float4*)xbuf[(p + 1) & 1];
#pragma unroll
                for (int q2 = 0; q2 < 4; ++q2) dst[lane + q2 * 64] = src[lane + q2 * 64];
            }
        }
        __syncthreads();
    }
}

extern "C" void kernel_launch(void* const* d_in, const int* in_sizes, int n_in,
                              void* d_out, int out_size, void* d_ws, size_t ws_size,
                              hipStream_t stream) {
    const float* ce  = (const float*)d_in[0];
    const float* w1  = (const float*)d_in[1];
    const float* b1  = (const float*)d_in[2];
    const float* g1  = (const float*)d_in[3];
    const float* be1 = (const float*)d_in[4];
    const float* Wih = (const float*)d_in[5];
    const float* bih = (const float*)d_in[6];
    const float* Whh = (const float*)d_in[7];
    const float* bhh = (const float*)d_in[8];
    const float* w2  = (const float*)d_in[9];
    const float* b2  = (const float*)d_in[10];
    const float* g2  = (const float*)d_in[11];
    const float* be2 = (const float*)d_in[12];
    float* out = (float*)d_out;

    const int nrows = in_sizes[0] / 6;   // B*T
    const int B = nrows / TST;           // 256

    k_inproj<<<(nrows + 3) / 4, 256, 0, stream>>>(ce, w1, b1, g1, be1, out, nrows);
    k_gru<<<B, 256, 0, stream>>>(out, Wih, bih, Whh, bhh, w2, b2, g2, be2);
}

// Round 12
// 1795.753 us; speedup vs baseline: 1.8776x; 1.0740x over previous
//
#include <hip/hip_runtime.h>
#include <math.h>

#define HID 64
#define TST 2048
#define CH 16              // timesteps per chunk
#define NCH (TST / CH)     // 128 chunks
#define EPSN 1e-5f

typedef float v2f __attribute__((ext_vector_type(2)));

#define REP32(M) M(0) M(1) M(2) M(3) M(4) M(5) M(6) M(7) \
                 M(8) M(9) M(10) M(11) M(12) M(13) M(14) M(15) \
                 M(16) M(17) M(18) M(19) M(20) M(21) M(22) M(23) \
                 M(24) M(25) M(26) M(27) M(28) M(29) M(30) M(31)

// ---------------------------------------------------------------------------
// Kernel 1: x = GELU(LayerNorm(ce @ w1 + b1))  -> staged into d_out (unchanged)
// ---------------------------------------------------------------------------
__global__ void k_inproj(const float* __restrict__ ce, const float* __restrict__ w1,
                         const float* __restrict__ b1, const float* __restrict__ g1,
                         const float* __restrict__ be1, float* __restrict__ xout,
                         int nrows) {
    const int lane = threadIdx.x & 63;
    const int wave = threadIdx.x >> 6;
    const long row = (long)blockIdx.x * 4 + wave;
    if (row >= nrows) return;
    const float* cr = ce + row * 6;
    float acc = b1[lane];
    acc += cr[0] * w1[0 * HID + lane];
    acc += cr[1] * w1[1 * HID + lane];
    acc += cr[2] * w1[2 * HID + lane];
    acc += cr[3] * w1[3 * HID + lane];
    acc += cr[4] * w1[4 * HID + lane];
    acc += cr[5] * w1[5 * HID + lane];
    float s = acc;
#pragma unroll
    for (int m = 32; m >= 1; m >>= 1) s += __shfl_xor(s, m, 64);
    const float mean = s * (1.0f / 64.0f);
    const float d = acc - mean;
    float q = d * d;
#pragma unroll
    for (int m = 32; m >= 1; m >>= 1) q += __shfl_xor(q, m, 64);
    const float var = q * (1.0f / 64.0f);
    const float xn = d * rsqrtf(var + EPSN) * g1[lane] + be1[lane];
    const float ge = 0.5f * xn * (1.0f + erff(xn * 0.70710678118654752440f));
    xout[row * HID + lane] = ge;
}

// ---------------------------------------------------------------------------
// Kernel 2: GRU scan, 4 waves (R8 structure) with PER-CHUNK AGPR re-pins.
//
// Evidence matrix (R8 vs R11):
//   R8:  one-time pin  -> VGPR 132 = weights SPILLED to L2-resident scratch
//        (WRITE_SIZE can't see L2-resident scratch; R8's 1840 cy/step =
//        ~500 cy chain + ~1300 cy serialized scratch reloads) -> 1570 us.
//   R11: per-STEP pins -> VGPR 212 = RESIDENT, but 1536 asm fences/chunk
//        serialize the FMA stream -> 1777 us, VALUBusy 40%.
// Untested cell: resident + fences once per CHUNK. Re-pin at the top of
// each p-iteration (outside the t-loop): 4 fence clusters/chunk, t-loop
// interior fence-free; worst case RA spills between chunks and pays ONE
// reload per chunk (3 cy/step amortized). "+a" values are non-remattable,
// so the only RA choices are keep-in-AGPR or visible spill.
//   wave 0: A/B/C = W_hh gate rows (192 AGPRs), serial scan via hbuf.
//   wave 1: A/B = W_ih r/n rows;  wave 2: A = W_ih z rows (gi chunk p).
//   wave 3: A = w2 column, LN epilogue chunk p-2 + x prefetch.
// ---------------------------------------------------------------------------
__global__ __launch_bounds__(256, 1)
__attribute__((amdgpu_waves_per_eu(1, 1)))
void k_gru(float* xo,
           const float* __restrict__ W_ih, const float* __restrict__ b_ih,
           const float* __restrict__ W_hh, const float* __restrict__ b_hh,
           const float* __restrict__ w2, const float* __restrict__ b2,
           const float* __restrict__ g2, const float* __restrict__ be2) {
    __shared__ __align__(16) float4 xbuf[2][CH][16];    // 8 KB  x chunks
    __shared__ __align__(16) float gibuf[2][CH][192];   // 24 KB gi preacts
    __shared__ __align__(16) float hist[2][CH][HID];    // 8 KB  h history
    __shared__ __align__(16) float hbuf[HID];           // h broadcast (wave 0)

    const int tid = threadIdx.x;
    const int lane = tid & 63;
    const int wv = tid >> 6;
    float* xb = xo + (size_t)blockIdx.x * TST * HID;

#define DECLW(i) v2f A##i = {0.f, 0.f}, B##i = {0.f, 0.f}, C##i = {0.f, 0.f};
    REP32(DECLW)
    float sc0 = 0.f, sc1 = 0.f, sc2 = 0.f;   // per-wave scalar params

    if (wv == 0) {
        const v2f* r0 = (const v2f*)(W_hh + (size_t)lane * HID);
        const v2f* r1 = (const v2f*)(W_hh + (size_t)(64 + lane) * HID);
        const v2f* r2 = (const v2f*)(W_hh + (size_t)(128 + lane) * HID);
#define LW0(i) A##i = r0[i]; B##i = r1[i]; C##i = r2[i];
        REP32(LW0)
        sc0 = b_hh[lane]; sc1 = b_hh[64 + lane]; sc2 = b_hh[128 + lane];
        hbuf[lane] = 0.0f;
    } else if (wv == 1) {
        const v2f* rA = (const v2f*)(W_ih + (size_t)lane * HID);
        const v2f* rB = (const v2f*)(W_ih + (size_t)(128 + lane) * HID);
#define LW1(i) A##i = rA[i]; B##i = rB[i];
        REP32(LW1)
        sc0 = b_ih[lane]; sc1 = b_ih[128 + lane];
    } else if (wv == 2) {
        const v2f* rC = (const v2f*)(W_ih + (size_t)(64 + lane) * HID);
#define LW2(i) A##i = rC[i];
        REP32(LW2)
        sc0 = b_ih[64 + lane];
    } else {
#define LW3(i) A##i.x = w2[(size_t)(2 * (i)) * HID + lane]; \
               A##i.y = w2[(size_t)(2 * (i) + 1) * HID + lane];
        REP32(LW3)
        sc0 = b2[lane]; sc1 = g2[lane]; sc2 = be2[lane];
    }

    // Initial park in the AGPR file.
#define PINW(i) asm volatile("" : "+a"(A##i), "+a"(B##i), "+a"(C##i));
    REP32(PINW)

    {
        const float4* src = (const float4*)xb;
        ((float4*)xbuf[0])[tid] = src[tid];
    }
    float h_reg = 0.0f;
    __syncthreads();

    for (int p = 0; p <= NCH + 1; ++p) {
        if (wv == 0) {
            if (p >= 1 && p <= NCH) {
                REP32(PINW)          // per-CHUNK residency re-assert (not per step)
                const int c = p - 1;
                const float* gp = (const float*)gibuf[c & 1];
                float* hp = (float*)hist[c & 1];
#pragma unroll 1
                for (int t = 0; t < CH; ++t) {
                    const float gr = gp[t * 192 + lane];
                    const float gz = gp[t * 192 + 64 + lane];
                    const float gn = gp[t * 192 + 128 + lane];
                    const v2f* hv = (const v2f*)hbuf;
                    // 2-way split accumulators: halve the dependent FMA chain
                    v2f ar0 = {0.f, 0.f}, ar1 = {0.f, 0.f};
                    v2f az0 = {0.f, 0.f}, az1 = {0.f, 0.f};
                    v2f an0 = {0.f, 0.f}, an1 = {0.f, 0.f};
#define SFMA(i) { const v2f h2 = hv[i]; \
                  if ((i) & 1) { ar1 += A##i * h2; az1 += B##i * h2; an1 += C##i * h2; } \
                  else         { ar0 += A##i * h2; az0 += B##i * h2; an0 += C##i * h2; } }
                    REP32(SFMA)
                    const v2f arv = ar0 + ar1;
                    const v2f azv = az0 + az1;
                    const v2f anv = an0 + an1;
                    const float rpre = gr + arv.x + arv.y + sc0;
                    const float zpre = gz + azv.x + azv.y + sc1;
                    const float hn = anv.x + anv.y + sc2;
                    const float r = 1.0f / (1.0f + __expf(-rpre));
                    const float z = 1.0f / (1.0f + __expf(-zpre));
                    const float pre = gn + r * hn;
                    const float e2 = __expf(2.0f * pre);
                    const float n = 1.0f - 2.0f / (e2 + 1.0f);
                    h_reg = (1.0f - z) * n + z * h_reg;
                    hbuf[lane] = h_reg;
                    hp[t * HID + lane] = h_reg;
                }
            }
        } else if (wv == 1 || wv == 2) {
            if (p < NCH) {
                REP32(PINW)          // per-CHUNK residency re-assert
                const float4* xc = (const float4*)xbuf[p & 1];
                float* gp = (float*)gibuf[p & 1];
#pragma unroll 1
                for (int t = 0; t < CH; ++t) {
                    const v2f* xv = (const v2f*)(xc + t * 16);
                    v2f aA0 = {0.f, 0.f}, aA1 = {0.f, 0.f};
                    v2f aB0 = {0.f, 0.f}, aB1 = {0.f, 0.f};
                    if (wv == 1) {
#define GFMA1(i) { const v2f x2 = xv[i]; \
                   if ((i) & 1) { aA1 += A##i * x2; aB1 += B##i * x2; } \
                   else         { aA0 += A##i * x2; aB0 += B##i * x2; } }
                        REP32(GFMA1)
                        gp[t * 192 + lane] = aA0.x + aA0.y + aA1.x + aA1.y + sc0;
                        gp[t * 192 + 128 + lane] = aB0.x + aB0.y + aB1.x + aB1.y + sc1;
                    } else {
#define GFMA2(i) { const v2f x2 = xv[i]; \
                   if ((i) & 1) { aA1 += A##i * x2; } \
                   else         { aA0 += A##i * x2; } }
                        REP32(GFMA2)
                        gp[t * 192 + 64 + lane] = aA0.x + aA0.y + aA1.x + aA1.y + sc0;
                    }
                }
            }
        } else {
            // ---- epilogue for chunk p-2: LN over 16 timesteps, 2 halves of 8 ----
            if (p >= 2) {
                REP32(PINW)          // per-CHUNK residency re-assert
                const int ce = p - 2;
                const float* hp = (const float*)hist[ce & 1];
#pragma unroll 1
                for (int half = 0; half < 2; ++half) {
                    float yv[8], sv[8], qv[8];
#pragma unroll
                    for (int u = 0; u < 8; ++u) {
                        const int t = half * 8 + u;
                        const v2f* hr = (const v2f*)(hp + t * HID);
                        v2f a20 = {0.f, 0.f}, a21 = {0.f, 0.f};
#define EFMA(i) { const v2f h2 = hr[i]; \
                  if ((i) & 1) { a21 += A##i * h2; } else { a20 += A##i * h2; } }
                        REP32(EFMA)
                        yv[u] = sc0 + a20.x + a20.y + a21.x + a21.y;
                    }
#pragma unroll
                    for (int u = 0; u < 8; ++u) { sv[u] = yv[u]; qv[u] = yv[u] * yv[u]; }
#pragma unroll
                    for (int m = 32; m >= 1; m >>= 1) {
#pragma unroll
                        for (int u = 0; u < 8; ++u) sv[u] += __shfl_xor(sv[u], m, 64);
#pragma unroll
                        for (int u = 0; u < 8; ++u) qv[u] += __shfl_xor(qv[u], m, 64);
                    }
#pragma unroll
                    for (int u = 0; u < 8; ++u) {
                        const int t = half * 8 + u;
                        const float mean = sv[u] * (1.0f / 64.0f);
                        const float var = qv[u] * (1.0f / 64.0f) - mean * mean;
                        const float dd = yv[u] - mean;
                        xb[(size_t)(ce * CH + t) * HID + lane] =
                            dd * rsqrtf(var + EPSN) * sc1 + sc2;
                    }
                }
            }
            // prefetch x chunk p+1
            if (p + 1 < NCH) {
                const float4* src = (const float4*)(xb + (size_t)(p + 1) * CH * HID);
                float4* dst = (float4*)xbuf[(p + 1) & 1];
#pragma unroll
                for (int q2 = 0; q2 < 4; ++q2) dst[lane + q2 * 64] = src[lane + q2 * 64];
            }
        }
        __syncthreads();
    }
}

extern "C" void kernel_launch(void* const* d_in, const int* in_sizes, int n_in,
                              void* d_out, int out_size, void* d_ws, size_t ws_size,
                              hipStream_t stream) {
    const float* ce  = (const float*)d_in[0];
    const float* w1  = (const float*)d_in[1];
    const float* b1  = (const float*)d_in[2];
    const float* g1  = (const float*)d_in[3];
    const float* be1 = (const float*)d_in[4];
    const float* Wih = (const float*)d_in[5];
    const float* bih = (const float*)d_in[6];
    const float* Whh = (const float*)d_in[7];
    const float* bhh = (const float*)d_in[8];
    const float* w2  = (const float*)d_in[9];
    const float* b2  = (const float*)d_in[10];
    const float* g2  = (const float*)d_in[11];
    const float* be2 = (const float*)d_in[12];
    float* out = (float*)d_out;

    const int nrows = in_sizes[0] / 6;   // B*T
    const int B = nrows / TST;           // 256

    k_inproj<<<(nrows + 3) / 4, 256, 0, stream>>>(ce, w1, b1, g1, be1, out, nrows);
    k_gru<<<B, 256, 0, stream>>>(out, Wih, bih, Whh, bhh, w2, b2, g2, be2);
}